// Round 3
// baseline (879.167 us; speedup 1.0000x reference)
//
#include <hip/hip_runtime.h>

// GCN: out = prelu(GCNConv2(prelu(GCNConv1(x)))), proj = MLP(out)
// R5: agg128 edge loop unrolled (latency -> many gathers in flight).
// R6: GEMM: B fragments register-resident, operand-swapped MFMA -> coalesced
//     float4 C stores.
// R7: fuse GEMM pairs (W1+W2, fc1+fc2) per 16-row strip: phase-1 result is
//     split to bf16 hi/lo in LDS (XOR-swizzled, 2-way conflicts = free) and
//     consumed by phase-2 as MFMA A-fragments. Saves ~400 MB of HBM
//     round-trips + 3 launches. agg batches widened 8->12.

typedef __attribute__((ext_vector_type(4))) float  f32x4;
typedef __attribute__((ext_vector_type(8))) __bf16 bf16x8;
typedef __attribute__((ext_vector_type(8))) short  short8;

__device__ __forceinline__ bf16x8 as_bf(short8 s) {
    union { short8 s; bf16x8 b; } u; u.s = s; return u.b;
}

// truncation split: x = hi + lo + eps, |eps| <= 2^-16 |x|
__device__ __forceinline__ short2 split1(float x) {
    unsigned u = __float_as_uint(x);
    short hi = (short)(u >> 16);
    float hif = __uint_as_float(u & 0xFFFF0000u);
    short lo = (short)(__float_as_uint(x - hif) >> 16);
    return make_short2(hi, lo);
}

__device__ __forceinline__ unsigned pack2(short a, short b) {
    return ((unsigned)(unsigned short)a) | ((unsigned)(unsigned short)b << 16);
}

// ---------------- degree count ----------------
__global__ void deg_kernel(const int* __restrict__ dst, int* __restrict__ deg, int E) {
    int e = blockIdx.x * blockDim.x + threadIdx.x;
    if (e < E) atomicAdd(&deg[dst[e]], 1);
}

// ---------------- scan phase 1: per-block (1024 elems) sum + dinv ----------------
__global__ __launch_bounds__(256)
void part_kernel(const int* __restrict__ deg, int* __restrict__ bsum,
                 float* __restrict__ dinv, int n) {
    int tid = threadIdx.x;
    int base = blockIdx.x * 1024 + tid * 4;
    int d[4] = {0, 0, 0, 0};
    if (base + 3 < n) {
        int4 v = *(const int4*)(deg + base);
        d[0] = v.x; d[1] = v.y; d[2] = v.z; d[3] = v.w;
    } else {
        for (int j = 0; j < 4; ++j) if (base + j < n) d[j] = deg[base + j];
    }
    for (int j = 0; j < 4; ++j)
        if (base + j < n) dinv[base + j] = rsqrtf((float)(d[j] + 1));
    int s = d[0] + d[1] + d[2] + d[3];
    for (int off = 32; off > 0; off >>= 1) s += __shfl_down(s, off);
    __shared__ int wsum[4];
    if ((tid & 63) == 0) wsum[tid >> 6] = s;
    __syncthreads();
    if (tid == 0) bsum[blockIdx.x] = wsum[0] + wsum[1] + wsum[2] + wsum[3];
}

// ---------------- scan phase 2: single block over block sums ----------------
__global__ __launch_bounds__(1024)
void topscan_kernel(const int* __restrict__ bsum, int* __restrict__ bbase, int nb) {
    __shared__ int sh[1024];
    int tid = threadIdx.x;
    int own = (tid < nb) ? bsum[tid] : 0;
    sh[tid] = own;
    __syncthreads();
    for (int off = 1; off < 1024; off <<= 1) {
        int t = (tid >= off) ? sh[tid - off] : 0;
        __syncthreads();
        sh[tid] += t;
        __syncthreads();
    }
    if (tid < nb) bbase[tid] = sh[tid] - own;   // exclusive
}

// ---------------- scan phase 3: per-block local scan + base -> offsets ----------------
__global__ __launch_bounds__(256)
void offs_kernel(const int* __restrict__ deg, const int* __restrict__ bbase,
                 int* __restrict__ offsets, int n) {
    int tid = threadIdx.x;
    int base = blockIdx.x * 1024 + tid * 4;
    int d[4] = {0, 0, 0, 0};
    if (base + 3 < n) {
        int4 v = *(const int4*)(deg + base);
        d[0] = v.x; d[1] = v.y; d[2] = v.z; d[3] = v.w;
    } else {
        for (int j = 0; j < 4; ++j) if (base + j < n) d[j] = deg[base + j];
    }
    int s = d[0] + d[1] + d[2] + d[3];
    __shared__ int sh[256];
    sh[tid] = s;
    __syncthreads();
    for (int off = 1; off < 256; off <<= 1) {
        int t = (tid >= off) ? sh[tid - off] : 0;
        __syncthreads();
        sh[tid] += t;
        __syncthreads();
    }
    int run = bbase[blockIdx.x] + sh[tid] - s;   // exclusive prefix for this thread
    for (int j = 0; j < 4; ++j) {
        int idx = base + j;
        if (idx <= n) offsets[idx] = run;        // also writes offsets[n]
        if (idx < n) run += d[j];
    }
}

// ---------------- CSR fill ----------------
__global__ void fill_kernel(const int* __restrict__ src, const int* __restrict__ dst,
                            const int* __restrict__ offsets, int* __restrict__ cursor,
                            int* __restrict__ csr, int E) {
    int e = blockIdx.x * blockDim.x + threadIdx.x;
    if (e < E) {
        int d = dst[e];
        int pos = offsets[d] + atomicAdd(&cursor[d], 1);
        csr[pos] = src[e];
    }
}

// ---------------- weight convert: W[K][N] fp32 -> Wt_hi/lo[n][k] bf16 ----------------
__global__ void wconv_kernel(const float* __restrict__ W, short* __restrict__ Wt_hi,
                             short* __restrict__ Wt_lo, int K, int N) {
    int idx = blockIdx.x * blockDim.x + threadIdx.x;
    if (idx >= K * N) return;
    int nn = idx / K, kk = idx - nn * K;
    short2 s = split1(W[(size_t)kk * N + nn]);
    Wt_hi[idx] = s.x;
    Wt_lo[idx] = s.y;
}

// ---------------- aggregation over dim-128 rows, 1 wave per node ----------------
// out[v] = epi( dinv[v] * ( dinv[v]*g[v] + sum_{s->v} dinv[s]*g[s] ) )
// Edge loop 12-wide: 12 independent 512B row-gathers in flight per wave.
// Tail predicated (index clamped, weight 0 -> exact).
__global__ __launch_bounds__(256)
void agg128_kernel(const float* __restrict__ g, const int* __restrict__ csr,
                   const int* __restrict__ offsets, const float* __restrict__ dinv,
                   const float* __restrict__ bias, const float* __restrict__ a_ptr,
                   float* __restrict__ out, int n) {
    int w = threadIdx.x >> 6;
    int lane = threadIdx.x & 63;
    int v = blockIdx.x * 4 + w;
    if (v >= n) return;
    const char* gb = (const char*)g;          // 32-bit voffset form (51.2 MB buffer)
    unsigned loff = (unsigned)lane * 8u;
    float dv = dinv[v];
    float2 self = *(const float2*)(gb + ((unsigned)v * 512u + loff));
    float accx = dv * self.x;
    float accy = dv * self.y;
    int e = offsets[v], end = offsets[v + 1];
#pragma unroll 1
    for (; e < end; e += 12) {
        int   idx[12];
        float dd[12];
        float2 mm[12];
#pragma unroll
        for (int j = 0; j < 12; ++j) {
            int ee = e + j;
            idx[j] = csr[ee < end ? ee : end - 1];   // clamped dup -> cache hit
        }
#pragma unroll
        for (int j = 0; j < 12; ++j)
            dd[j] = (e + j < end) ? dinv[idx[j]] : 0.f;
#pragma unroll
        for (int j = 0; j < 12; ++j)
            mm[j] = *(const float2*)(gb + ((unsigned)idx[j] * 512u + loff));
#pragma unroll
        for (int j = 0; j < 12; ++j) {
            accx += dd[j] * mm[j].x;
            accy += dd[j] * mm[j].y;
        }
    }
    accx *= dv;
    accy *= dv;
    if (bias) {
        float a = *a_ptr;
        float2 bb = ((const float2*)bias)[lane];
        accx += bb.x;
        accy += bb.y;
        accx = accx >= 0.f ? accx : a * accx;
        accy = accy >= 0.f ? accy : a * accy;
    }
    float2 r; r.x = accx; r.y = accy;
    ((float2*)out)[(size_t)v * 64 + lane] = r;
}

// ---------------- fused GEMM pair: C = epi2( act1(A@B1 + mb) @ B2 + b2 ) ------
// Strip = 16 rows. 256 thr = 4 waves; wave w covers cols w*(N1/4) in phase 1,
// cols w*(N2/4) in phase 2. B frags register-resident. Phase-1 result (after
// mid bias + prelu(am), am=0 == relu) is split1() to bf16 hi/lo planes in LDS
// (XOR swizzle byte^=(row&7)<<4 -> 2-way bank = free) and read back as MFMA
// A-fragments in phase 2. Identical arithmetic to store-fp32-then-split path.
// In-place C==A is safe: each block touches only its own 16 rows, reads first.
template<int K1, int N1, int N2>
__global__ __launch_bounds__(256)
void fused2_kernel(const float* __restrict__ A,
                   const short* __restrict__ B1h, const short* __restrict__ B1l,
                   const short* __restrict__ B2h, const short* __restrict__ B2l,
                   float* __restrict__ C, int M,
                   const float* __restrict__ midbias,
                   const float* __restrict__ mid_a,     // null -> relu (slope 0)
                   const float* __restrict__ bias2) {
    constexpr int KT1 = K1 / 32;
    constexpr int T1  = N1 / 64;      // 16-col tiles per wave, phase 1
    constexpr int KT2 = N1 / 32;      // K2 = N1
    constexpr int T2  = N2 / 64;      // 16-col tiles per wave, phase 2
    __shared__ short hs[16 * N1];
    __shared__ short ls[16 * N1];

    const int tid  = threadIdx.x;
    const int w    = tid >> 6, lane = tid & 63;
    const int quad = lane >> 4, l16 = lane & 15;
    const int colb1 = w * (N1 / 4);
    const int colb2 = w * (N2 / 4);
    const unsigned sw = (unsigned)(l16 & 7) << 4;

    const int m  = blockIdx.x * 16 + l16;
    const int mc = m < M ? m : blockIdx.x * 16;   // clamp within own strip (race-free)

    // ---- phase 1: h = act1(A @ B1 + midbias) ----
    bf16x8 bf[T1][KT1][2];
#pragma unroll
    for (int t = 0; t < T1; ++t)
#pragma unroll
        for (int kt = 0; kt < KT1; ++kt) {
            size_t off = (size_t)(colb1 + t * 16 + l16) * K1 + kt * 32 + quad * 8;
            bf[t][kt][0] = as_bf(*(const short8*)(B1h + off));
            bf[t][kt][1] = as_bf(*(const short8*)(B1l + off));
        }
    const float* Ap = A + (size_t)mc * K1 + quad * 8;
    float4 av[KT1 * 2];
#pragma unroll
    for (int kt = 0; kt < KT1; ++kt) {
        av[2 * kt]     = *(const float4*)(Ap + kt * 32);
        av[2 * kt + 1] = *(const float4*)(Ap + kt * 32 + 4);
    }
    f32x4 acc[T1];
#pragma unroll
    for (int t = 0; t < T1; ++t) acc[t] = (f32x4){0.f, 0.f, 0.f, 0.f};

#pragma unroll
    for (int kt = 0; kt < KT1; ++kt) {
        float4 v0 = av[2 * kt], v1 = av[2 * kt + 1];
        short8 ah, al;
        short2 s;
        s = split1(v0.x); ah[0] = s.x; al[0] = s.y;
        s = split1(v0.y); ah[1] = s.x; al[1] = s.y;
        s = split1(v0.z); ah[2] = s.x; al[2] = s.y;
        s = split1(v0.w); ah[3] = s.x; al[3] = s.y;
        s = split1(v1.x); ah[4] = s.x; al[4] = s.y;
        s = split1(v1.y); ah[5] = s.x; al[5] = s.y;
        s = split1(v1.z); ah[6] = s.x; al[6] = s.y;
        s = split1(v1.w); ah[7] = s.x; al[7] = s.y;
        bf16x8 a_hi = as_bf(ah), a_lo = as_bf(al);
#pragma unroll
        for (int t = 0; t < T1; ++t) {
            acc[t] = __builtin_amdgcn_mfma_f32_16x16x32_bf16(bf[t][kt][0], a_hi, acc[t], 0, 0, 0);
            acc[t] = __builtin_amdgcn_mfma_f32_16x16x32_bf16(bf[t][kt][1], a_hi, acc[t], 0, 0, 0);
            acc[t] = __builtin_amdgcn_mfma_f32_16x16x32_bf16(bf[t][kt][0], a_lo, acc[t], 0, 0, 0);
        }
    }

    const float am = mid_a ? *mid_a : 0.f;        // prelu slope; 0 == relu
#pragma unroll
    for (int t = 0; t < T1; ++t) {
        const int col = colb1 + t * 16 + quad * 4;
        const float4 bb = *(const float4*)(midbias + col);
        float v0 = acc[t][0] + bb.x; v0 = v0 >= 0.f ? v0 : am * v0;
        float v1 = acc[t][1] + bb.y; v1 = v1 >= 0.f ? v1 : am * v1;
        float v2 = acc[t][2] + bb.z; v2 = v2 >= 0.f ? v2 : am * v2;
        float v3 = acc[t][3] + bb.w; v3 = v3 >= 0.f ? v3 : am * v3;
        short2 s0 = split1(v0), s1 = split1(v1), s2 = split1(v2), s3 = split1(v3);
        uint2 hp, lp;
        hp.x = pack2(s0.x, s1.x); hp.y = pack2(s2.x, s3.x);
        lp.x = pack2(s0.y, s1.y); lp.y = pack2(s2.y, s3.y);
        const unsigned off = ((unsigned)(l16 * N1 + col) * 2u) ^ sw;
        *(uint2*)((char*)hs + off) = hp;
        *(uint2*)((char*)ls + off) = lp;
    }
    __syncthreads();

    // ---- phase 2: C = h @ B2 (+ bias2) ----
    bf16x8 b2[T2][KT2][2];
#pragma unroll
    for (int t = 0; t < T2; ++t)
#pragma unroll
        for (int kt = 0; kt < KT2; ++kt) {
            size_t off = (size_t)(colb2 + t * 16 + l16) * N1 + kt * 32 + quad * 8;
            b2[t][kt][0] = as_bf(*(const short8*)(B2h + off));
            b2[t][kt][1] = as_bf(*(const short8*)(B2l + off));
        }
    f32x4 acc2[T2];
#pragma unroll
    for (int t = 0; t < T2; ++t) acc2[t] = (f32x4){0.f, 0.f, 0.f, 0.f};

#pragma unroll
    for (int kt = 0; kt < KT2; ++kt) {
        const unsigned off = ((unsigned)(l16 * N1 + kt * 32 + quad * 8) * 2u) ^ sw;
        bf16x8 a_hi = *(const bf16x8*)((const char*)hs + off);
        bf16x8 a_lo = *(const bf16x8*)((const char*)ls + off);
#pragma unroll
        for (int t = 0; t < T2; ++t) {
            acc2[t] = __builtin_amdgcn_mfma_f32_16x16x32_bf16(b2[t][kt][0], a_hi, acc2[t], 0, 0, 0);
            acc2[t] = __builtin_amdgcn_mfma_f32_16x16x32_bf16(b2[t][kt][1], a_hi, acc2[t], 0, 0, 0);
            acc2[t] = __builtin_amdgcn_mfma_f32_16x16x32_bf16(b2[t][kt][0], a_lo, acc2[t], 0, 0, 0);
        }
    }

    if (m < M) {
        float* Crow = C + (size_t)m * N2 + colb2 + quad * 4;
#pragma unroll
        for (int t = 0; t < T2; ++t) {
            float4 v;
            v.x = acc2[t][0]; v.y = acc2[t][1]; v.z = acc2[t][2]; v.w = acc2[t][3];
            if (bias2) {
                const float4 bb = *(const float4*)(bias2 + colb2 + t * 16 + quad * 4);
                v.x += bb.x; v.y += bb.y; v.z += bb.z; v.w += bb.w;
            }
            *(float4*)(Crow + t * 16) = v;
        }
    }
}

extern "C" void kernel_launch(void* const* d_in, const int* in_sizes, int n_in,
                              void* d_out, int out_size, void* d_ws, size_t ws_size,
                              hipStream_t stream) {
    const float* x     = (const float*)d_in[0];
    const int*   ei    = (const int*)d_in[1];   // harness materializes int64 as int32
    const float* W1    = (const float*)d_in[2];
    const float* b1    = (const float*)d_in[3];
    const float* W2    = (const float*)d_in[4];
    const float* b2    = (const float*)d_in[5];
    const float* a_ptr = (const float*)d_in[6];
    const float* fc1_w = (const float*)d_in[7];
    const float* fc1_b = (const float*)d_in[8];
    const float* fc2_w = (const float*)d_in[9];
    const float* fc2_b = (const float*)d_in[10];

    const int n = in_sizes[0] / 128;
    const int E = in_sizes[1] / 2;
    const int* src = ei;
    const int* dst = ei + E;
    const int nb = (n + 1023) >> 10;            // scan blocks (98 for n=100000)

    float* out_final  = (float*)d_out;                    // [n,128]
    float* proj_final = out_final + (size_t)n * 128;      // [n,128]

    // workspace carve-out (~59.6 MB total)
    char* p = (char*)d_ws;
    auto take = [&](size_t bytes) -> char* {
        char* q = p;
        p += (bytes + 1023) & ~(size_t)1023;
        return q;
    };
    int*   deg     = (int*)take((size_t)n * 4);
    int*   offsets = (int*)take(((size_t)n + 1) * 4);
    int*   cursor  = (int*)take((size_t)n * 4);
    float* dinv    = (float*)take((size_t)n * 4);
    int*   bsum    = (int*)take((size_t)1024 * 4);
    int*   bbase   = (int*)take((size_t)1024 * 4);
    int*   csr     = (int*)take((size_t)E * 4);
    short* W1t_hi  = (short*)take((size_t)256 * 128 * 2);
    short* W1t_lo  = (short*)take((size_t)256 * 128 * 2);
    short* W2t_hi  = (short*)take((size_t)128 * 256 * 2);
    short* W2t_lo  = (short*)take((size_t)128 * 256 * 2);
    short* f1t_hi  = (short*)take((size_t)128 * 128 * 2);
    short* f1t_lo  = (short*)take((size_t)128 * 128 * 2);
    short* f2t_hi  = (short*)take((size_t)128 * 128 * 2);
    short* f2t_lo  = (short*)take((size_t)128 * 128 * 2);
    float* bufA    = (float*)take((size_t)n * 128 * 4);   // [n,128] f32 scratch

    (void)hipMemsetAsync(deg, 0, (size_t)n * 4, stream);
    (void)hipMemsetAsync(cursor, 0, (size_t)n * 4, stream);

    // ---- weight pre-transpose/split (tiny) ----
    wconv_kernel<<<(128 * 256 + 255) / 256, 256, 0, stream>>>(W1, W1t_hi, W1t_lo, 128, 256);
    wconv_kernel<<<(256 * 128 + 255) / 256, 256, 0, stream>>>(W2, W2t_hi, W2t_lo, 256, 128);
    wconv_kernel<<<(128 * 128 + 255) / 256, 256, 0, stream>>>(fc1_w, f1t_hi, f1t_lo, 128, 128);
    wconv_kernel<<<(128 * 128 + 255) / 256, 256, 0, stream>>>(fc2_w, f2t_hi, f2t_lo, 128, 128);

    // ---- CSR build (shared by both conv layers) ----
    deg_kernel<<<(E + 255) / 256, 256, 0, stream>>>(dst, deg, E);
    part_kernel<<<nb, 256, 0, stream>>>(deg, bsum, dinv, n);
    topscan_kernel<<<1, 1024, 0, stream>>>(bsum, bbase, nb);
    offs_kernel<<<nb, 256, 0, stream>>>(deg, bbase, offsets, n);
    fill_kernel<<<(E + 255) / 256, 256, 0, stream>>>(src, dst, offsets, cursor, csr, E);

    const int sblk = (n + 15) / 16;             // 16-row strips (6250)

    // ---- layer 1+2 linear parts, fused: bufA = prelu(aggx@W1+b1) @ W2
    agg128_kernel<<<(n + 3) / 4, 256, 0, stream>>>(x, csr, offsets, dinv,
                                                   nullptr, nullptr, bufA, n);
    fused2_kernel<128, 256, 128><<<sblk, 256, 0, stream>>>(
        bufA, W1t_hi, W1t_lo, W2t_hi, W2t_lo, bufA, n, b1, a_ptr, nullptr);

    // out = prelu(A_hat agg of bufA + b2) -> d_out[0 : n*128]
    agg128_kernel<<<(n + 3) / 4, 256, 0, stream>>>(bufA, csr, offsets, dinv,
                                                   b2, a_ptr, out_final, n);

    // ---- MLP head, fused: proj = relu(out@fc1+fc1_b) @ fc2 + fc2_b
    fused2_kernel<128, 128, 128><<<sblk, 256, 0, stream>>>(
        out_final, f1t_hi, f1t_lo, f2t_hi, f2t_lo, proj_final, n, fc1_b, nullptr, fc2_b);
}

// Round 4
// 778.211 us; speedup vs baseline: 1.1297x; 1.1297x over previous
//
#include <hip/hip_runtime.h>

// GCN: out = prelu(GCNConv2(prelu(GCNConv1(x)))), proj = MLP(out)
// R5: agg128 edge loop unrolled 12-wide (latency -> 12 gathers in flight).
// R6: GEMM: B fragments register-resident (multi-tile blocks), operand-swapped
//     MFMA -> coalesced float4 C stores.
// R8: (R7 fusion reverted - single-use B frags got sunk into dependent
//     load->MFMA chains, L2-latency-bound at VGPR=56.)
//     Weights stored FRAGMENT-CONTIGUOUS: wave's B-frag load = one coalesced
//     1KB request (was 16 half-used lines). W2 K=256 in ONE pass (wave tile
//     16x32, template<KT,T>), killing the out1 re-read + fp32 accum trip.

typedef __attribute__((ext_vector_type(4))) float  f32x4;
typedef __attribute__((ext_vector_type(8))) __bf16 bf16x8;
typedef __attribute__((ext_vector_type(8))) short  short8;

__device__ __forceinline__ bf16x8 as_bf(short8 s) {
    union { short8 s; bf16x8 b; } u; u.s = s; return u.b;
}

// truncation split: x = hi + lo + eps, |eps| <= 2^-16 |x|
__device__ __forceinline__ short2 split1(float x) {
    unsigned u = __float_as_uint(x);
    short hi = (short)(u >> 16);
    float hif = __uint_as_float(u & 0xFFFF0000u);
    short lo = (short)(__float_as_uint(x - hif) >> 16);
    return make_short2(hi, lo);
}

// ---------------- degree count ----------------
__global__ void deg_kernel(const int* __restrict__ dst, int* __restrict__ deg, int E) {
    int e = blockIdx.x * blockDim.x + threadIdx.x;
    if (e < E) atomicAdd(&deg[dst[e]], 1);
}

// ---------------- scan phase 1: per-block (1024 elems) sum + dinv ----------------
__global__ __launch_bounds__(256)
void part_kernel(const int* __restrict__ deg, int* __restrict__ bsum,
                 float* __restrict__ dinv, int n) {
    int tid = threadIdx.x;
    int base = blockIdx.x * 1024 + tid * 4;
    int d[4] = {0, 0, 0, 0};
    if (base + 3 < n) {
        int4 v = *(const int4*)(deg + base);
        d[0] = v.x; d[1] = v.y; d[2] = v.z; d[3] = v.w;
    } else {
        for (int j = 0; j < 4; ++j) if (base + j < n) d[j] = deg[base + j];
    }
    for (int j = 0; j < 4; ++j)
        if (base + j < n) dinv[base + j] = rsqrtf((float)(d[j] + 1));
    int s = d[0] + d[1] + d[2] + d[3];
    for (int off = 32; off > 0; off >>= 1) s += __shfl_down(s, off);
    __shared__ int wsum[4];
    if ((tid & 63) == 0) wsum[tid >> 6] = s;
    __syncthreads();
    if (tid == 0) bsum[blockIdx.x] = wsum[0] + wsum[1] + wsum[2] + wsum[3];
}

// ---------------- scan phase 2: single block over block sums ----------------
__global__ __launch_bounds__(1024)
void topscan_kernel(const int* __restrict__ bsum, int* __restrict__ bbase, int nb) {
    __shared__ int sh[1024];
    int tid = threadIdx.x;
    int own = (tid < nb) ? bsum[tid] : 0;
    sh[tid] = own;
    __syncthreads();
    for (int off = 1; off < 1024; off <<= 1) {
        int t = (tid >= off) ? sh[tid - off] : 0;
        __syncthreads();
        sh[tid] += t;
        __syncthreads();
    }
    if (tid < nb) bbase[tid] = sh[tid] - own;   // exclusive
}

// ---------------- scan phase 3: per-block local scan + base -> offsets ----------------
__global__ __launch_bounds__(256)
void offs_kernel(const int* __restrict__ deg, const int* __restrict__ bbase,
                 int* __restrict__ offsets, int n) {
    int tid = threadIdx.x;
    int base = blockIdx.x * 1024 + tid * 4;
    int d[4] = {0, 0, 0, 0};
    if (base + 3 < n) {
        int4 v = *(const int4*)(deg + base);
        d[0] = v.x; d[1] = v.y; d[2] = v.z; d[3] = v.w;
    } else {
        for (int j = 0; j < 4; ++j) if (base + j < n) d[j] = deg[base + j];
    }
    int s = d[0] + d[1] + d[2] + d[3];
    __shared__ int sh[256];
    sh[tid] = s;
    __syncthreads();
    for (int off = 1; off < 256; off <<= 1) {
        int t = (tid >= off) ? sh[tid - off] : 0;
        __syncthreads();
        sh[tid] += t;
        __syncthreads();
    }
    int run = bbase[blockIdx.x] + sh[tid] - s;   // exclusive prefix for this thread
    for (int j = 0; j < 4; ++j) {
        int idx = base + j;
        if (idx <= n) offsets[idx] = run;        // also writes offsets[n]
        if (idx < n) run += d[j];
    }
}

// ---------------- CSR fill ----------------
__global__ void fill_kernel(const int* __restrict__ src, const int* __restrict__ dst,
                            const int* __restrict__ offsets, int* __restrict__ cursor,
                            int* __restrict__ csr, int E) {
    int e = blockIdx.x * blockDim.x + threadIdx.x;
    if (e < E) {
        int d = dst[e];
        int pos = offsets[d] + atomicAdd(&cursor[d], 1);
        csr[pos] = src[e];
    }
}

// ---- weight convert: W[K][N] fp32 -> fragment-contiguous bf16 hi/lo planes ----
// Layout: elem o = ((nt*KT + kt)*64 + quad*16 + l16)*8 + j
//   maps to col n = nt*16 + l16, k = kt*32 + quad*8 + j.
// A wave's fragment load (64 lanes x 16B) is then one contiguous 1KB block.
__global__ void wconv_kernel(const float* __restrict__ W, short* __restrict__ Fh,
                             short* __restrict__ Fl, int K, int N, int ktlog) {
    int o = blockIdx.x * blockDim.x + threadIdx.x;
    if (o >= K * N) return;
    int j  = o & 7;
    int l  = (o >> 3) & 15;
    int q  = (o >> 7) & 3;
    int t2 = o >> 9;
    int kt = t2 & ((1 << ktlog) - 1);
    int nt = t2 >> ktlog;
    int nn = nt * 16 + l;
    int kk = kt * 32 + q * 8 + j;
    short2 s = split1(W[(size_t)kk * N + nn]);
    Fh[o] = s.x;
    Fl[o] = s.y;
}

// ---------------- aggregation over dim-128 rows, 1 wave per node ----------------
// out[v] = epi( dinv[v] * ( dinv[v]*g[v] + sum_{s->v} dinv[s]*g[s] ) )
// Edge loop 12-wide: 12 independent 512B row-gathers in flight per wave.
__global__ __launch_bounds__(256)
void agg128_kernel(const float* __restrict__ g, const int* __restrict__ csr,
                   const int* __restrict__ offsets, const float* __restrict__ dinv,
                   const float* __restrict__ bias, const float* __restrict__ a_ptr,
                   float* __restrict__ out, int n) {
    int w = threadIdx.x >> 6;
    int lane = threadIdx.x & 63;
    int v = blockIdx.x * 4 + w;
    if (v >= n) return;
    const char* gb = (const char*)g;          // 32-bit voffset form (51.2 MB buffer)
    unsigned loff = (unsigned)lane * 8u;
    float dv = dinv[v];
    float2 self = *(const float2*)(gb + ((unsigned)v * 512u + loff));
    float accx = dv * self.x;
    float accy = dv * self.y;
    int e = offsets[v], end = offsets[v + 1];
#pragma unroll 1
    for (; e < end; e += 12) {
        int   idx[12];
        float dd[12];
        float2 mm[12];
#pragma unroll
        for (int j = 0; j < 12; ++j) {
            int ee = e + j;
            idx[j] = csr[ee < end ? ee : end - 1];   // clamped dup -> cache hit
        }
#pragma unroll
        for (int j = 0; j < 12; ++j)
            dd[j] = (e + j < end) ? dinv[idx[j]] : 0.f;
#pragma unroll
        for (int j = 0; j < 12; ++j)
            mm[j] = *(const float2*)(gb + ((unsigned)idx[j] * 512u + loff));
#pragma unroll
        for (int j = 0; j < 12; ++j) {
            accx += dd[j] * mm[j].x;
            accy += dd[j] * mm[j].y;
        }
    }
    accx *= dv;
    accy *= dv;
    if (bias) {
        float a = *a_ptr;
        float2 bb = ((const float2*)bias)[lane];
        accx += bb.x;
        accy += bb.y;
        accx = accx >= 0.f ? accx : a * accx;
        accy = accy >= 0.f ? accy : a * accy;
    }
    float2 r; r.x = accx; r.y = accy;
    ((float2*)out)[(size_t)v * 64 + lane] = r;
}

// ---------------- split-bf16 MFMA GEMM, B register-resident, frag-coalesced ----
// C[M][N] = epi( A[M][lda] @ B + bias ), K = KT*32, wave tile 16 x (T*16).
// Block = 4 waves = 64 rows x (T*16) cols; tpb row-tiles per block amortize the
// B preload (B frags multi-use -> register-resident). B loads are contiguous
// 1KB per wave (fragment-order layout). act: 0=none, 1=relu, 2=prelu(a).
template<int KT, int T>
__global__ __launch_bounds__(256)
void gemm64_kernel(const float* __restrict__ A, int lda,
                   const short* __restrict__ Bh, const short* __restrict__ Bl,
                   float* __restrict__ C, int M, int N,
                   int mtiles, int tpb,
                   const float* __restrict__ bias, int act,
                   const float* __restrict__ a_ptr) {
    const int tid  = threadIdx.x;
    const int wave = tid >> 6, lane = tid & 63;
    const int quad = lane >> 4, l16 = lane & 15;
    const int col0 = blockIdx.y * (T * 16);
    const int nt0  = col0 >> 4;

    // B fragments, register-resident for the whole block lifetime.
    bf16x8 bf[T][KT][2];
#pragma unroll
    for (int t = 0; t < T; ++t)
#pragma unroll
        for (int kt = 0; kt < KT; ++kt) {
            size_t off = ((size_t)((nt0 + t) * KT + kt) << 9) + (lane << 3);
            bf[t][kt][0] = as_bf(*(const short8*)(Bh + off));
            bf[t][kt][1] = as_bf(*(const short8*)(Bl + off));
        }

    const float aw = (act == 2) ? *a_ptr : 0.f;

    const int t0 = blockIdx.x * tpb;
    const int t1 = (t0 + tpb < mtiles) ? t0 + tpb : mtiles;
    for (int tile = t0; tile < t1; ++tile) {
        const int m  = tile * 64 + wave * 16 + l16;
        const int mc = m < M ? m : M - 1;
        const float* Ap = A + (size_t)mc * lda + quad * 8;

        f32x4 acc[T];
#pragma unroll
        for (int t = 0; t < T; ++t) acc[t] = (f32x4){0.f, 0.f, 0.f, 0.f};

#pragma unroll
        for (int kh = 0; kh < KT / 4; ++kh) {
            float4 av[8];
#pragma unroll
            for (int kk = 0; kk < 4; ++kk) {
                av[2 * kk]     = *(const float4*)(Ap + (kh * 4 + kk) * 32);
                av[2 * kk + 1] = *(const float4*)(Ap + (kh * 4 + kk) * 32 + 4);
            }
#pragma unroll
            for (int kk = 0; kk < 4; ++kk) {
                const int kt = kh * 4 + kk;
                float4 v0 = av[2 * kk], v1 = av[2 * kk + 1];
                short8 ah, al;
                short2 s;
                s = split1(v0.x); ah[0] = s.x; al[0] = s.y;
                s = split1(v0.y); ah[1] = s.x; al[1] = s.y;
                s = split1(v0.z); ah[2] = s.x; al[2] = s.y;
                s = split1(v0.w); ah[3] = s.x; al[3] = s.y;
                s = split1(v1.x); ah[4] = s.x; al[4] = s.y;
                s = split1(v1.y); ah[5] = s.x; al[5] = s.y;
                s = split1(v1.z); ah[6] = s.x; al[6] = s.y;
                s = split1(v1.w); ah[7] = s.x; al[7] = s.y;
                bf16x8 a_hi = as_bf(ah), a_lo = as_bf(al);
#pragma unroll
                for (int t = 0; t < T; ++t) {
                    acc[t] = __builtin_amdgcn_mfma_f32_16x16x32_bf16(bf[t][kt][0], a_hi, acc[t], 0, 0, 0);
                    acc[t] = __builtin_amdgcn_mfma_f32_16x16x32_bf16(bf[t][kt][1], a_hi, acc[t], 0, 0, 0);
                    acc[t] = __builtin_amdgcn_mfma_f32_16x16x32_bf16(bf[t][kt][0], a_lo, acc[t], 0, 0, 0);
                }
            }
        }

        if (m < M) {
            float* Crow = C + (size_t)m * N + col0 + quad * 4;
#pragma unroll
            for (int t = 0; t < T; ++t) {
                float4 v;
                v.x = acc[t][0]; v.y = acc[t][1]; v.z = acc[t][2]; v.w = acc[t][3];
                if (bias) {
                    const float4 bb = *(const float4*)(bias + col0 + t * 16 + quad * 4);
                    v.x += bb.x; v.y += bb.y; v.z += bb.z; v.w += bb.w;
                }
                if (act == 1) {
                    v.x = fmaxf(v.x, 0.f); v.y = fmaxf(v.y, 0.f);
                    v.z = fmaxf(v.z, 0.f); v.w = fmaxf(v.w, 0.f);
                } else if (act == 2) {
                    v.x = v.x >= 0.f ? v.x : aw * v.x;
                    v.y = v.y >= 0.f ? v.y : aw * v.y;
                    v.z = v.z >= 0.f ? v.z : aw * v.z;
                    v.w = v.w >= 0.f ? v.w : aw * v.w;
                }
                *(float4*)(Crow + t * 16) = v;
            }
        }
    }
}

extern "C" void kernel_launch(void* const* d_in, const int* in_sizes, int n_in,
                              void* d_out, int out_size, void* d_ws, size_t ws_size,
                              hipStream_t stream) {
    const float* x     = (const float*)d_in[0];
    const int*   ei    = (const int*)d_in[1];   // harness materializes int64 as int32
    const float* W1    = (const float*)d_in[2];
    const float* b1    = (const float*)d_in[3];
    const float* W2    = (const float*)d_in[4];
    const float* b2    = (const float*)d_in[5];
    const float* a_ptr = (const float*)d_in[6];
    const float* fc1_w = (const float*)d_in[7];
    const float* fc1_b = (const float*)d_in[8];
    const float* fc2_w = (const float*)d_in[9];
    const float* fc2_b = (const float*)d_in[10];

    const int n = in_sizes[0] / 128;
    const int E = in_sizes[1] / 2;
    const int* src = ei;
    const int* dst = ei + E;
    const int nb = (n + 1023) >> 10;            // scan blocks (98 for n=100000)

    float* out_final  = (float*)d_out;                    // [n,128]
    float* proj_final = out_final + (size_t)n * 128;      // [n,128]
    float* out1       = (float*)d_out;                    // [n,256] transient

    // workspace carve-out (~59.6 MB total)
    char* p = (char*)d_ws;
    auto take = [&](size_t bytes) -> char* {
        char* q = p;
        p += (bytes + 1023) & ~(size_t)1023;
        return q;
    };
    int*   deg     = (int*)take((size_t)n * 4);
    int*   offsets = (int*)take(((size_t)n + 1) * 4);
    int*   cursor  = (int*)take((size_t)n * 4);
    float* dinv    = (float*)take((size_t)n * 4);
    int*   bsum    = (int*)take((size_t)1024 * 4);
    int*   bbase   = (int*)take((size_t)1024 * 4);
    int*   csr     = (int*)take((size_t)E * 4);
    short* W1t_hi  = (short*)take((size_t)256 * 128 * 2);
    short* W1t_lo  = (short*)take((size_t)256 * 128 * 2);
    short* W2t_hi  = (short*)take((size_t)128 * 256 * 2);
    short* W2t_lo  = (short*)take((size_t)128 * 256 * 2);
    short* f1t_hi  = (short*)take((size_t)128 * 128 * 2);
    short* f1t_lo  = (short*)take((size_t)128 * 128 * 2);
    short* f2t_hi  = (short*)take((size_t)128 * 128 * 2);
    short* f2t_lo  = (short*)take((size_t)128 * 128 * 2);
    float* bufA    = (float*)take((size_t)n * 128 * 4);   // [n,128] f32 scratch

    (void)hipMemsetAsync(deg, 0, (size_t)n * 4, stream);
    (void)hipMemsetAsync(cursor, 0, (size_t)n * 4, stream);

    // ---- weight pre-transpose/split into fragment order (tiny) ----
    wconv_kernel<<<(128 * 256 + 255) / 256, 256, 0, stream>>>(W1, W1t_hi, W1t_lo, 128, 256, 2);
    wconv_kernel<<<(256 * 128 + 255) / 256, 256, 0, stream>>>(W2, W2t_hi, W2t_lo, 256, 128, 3);
    wconv_kernel<<<(128 * 128 + 255) / 256, 256, 0, stream>>>(fc1_w, f1t_hi, f1t_lo, 128, 128, 2);
    wconv_kernel<<<(128 * 128 + 255) / 256, 256, 0, stream>>>(fc2_w, f2t_hi, f2t_lo, 128, 128, 2);

    // ---- CSR build (shared by both conv layers) ----
    deg_kernel<<<(E + 255) / 256, 256, 0, stream>>>(dst, deg, E);
    part_kernel<<<nb, 256, 0, stream>>>(deg, bsum, dinv, n);
    topscan_kernel<<<1, 1024, 0, stream>>>(bsum, bbase, nb);
    offs_kernel<<<nb, 256, 0, stream>>>(deg, bbase, offsets, n);
    fill_kernel<<<(E + 255) / 256, 256, 0, stream>>>(src, dst, offsets, cursor, csr, E);

    const int mtiles = (n + 63) / 64;
    const int TPB = 4;
    const int gx = (mtiles + TPB - 1) / TPB;

    // ---- layer 1: aggregate first (dim 128): aggx = A_hat x -> bufA
    agg128_kernel<<<(n + 3) / 4, 256, 0, stream>>>(x, csr, offsets, dinv,
                                                   nullptr, nullptr, bufA, n);
    // out1 = prelu(aggx @ W1 + b1) -> d_out as [n,256]
    gemm64_kernel<4, 4><<<dim3(gx, 4), 256, 0, stream>>>(
        bufA, 128, W1t_hi, W1t_lo, out1, n, 256, mtiles, TPB, b1, 2, a_ptr);

    // ---- layer 2: g2 = out1 @ W2 -> bufA [n,128]   (K=256, single pass)
    gemm64_kernel<8, 2><<<dim3(gx, 4), 256, 0, stream>>>(
        out1, 256, W2t_hi, W2t_lo, bufA, n, 128, mtiles, TPB, nullptr, 0, nullptr);
    // out = prelu(A_hat agg of bufA + b2) -> d_out[0 : n*128]
    agg128_kernel<<<(n + 3) / 4, 256, 0, stream>>>(bufA, csr, offsets, dinv,
                                                   b2, a_ptr, out_final, n);

    // ---- MLP head ----
    gemm64_kernel<4, 4><<<dim3(gx, 2), 256, 0, stream>>>(
        out_final, 128, f1t_hi, f1t_lo, bufA, n, 128, mtiles, TPB, fc1_b, 1, nullptr);
    gemm64_kernel<4, 4><<<dim3(gx, 2), 256, 0, stream>>>(
        bufA, 128, f2t_hi, f2t_lo, proj_final, n, 128, mtiles, TPB, fc2_b, 0, nullptr);
}